// Round 1
// baseline (32645.767 us; speedup 1.0000x reference)
//
#include <hip/hip_runtime.h>

#define B_ 32
#define P_ 2048
#define K_ 20

// Branchless top-K insert: list ascending worst->best.
// "better" = larger key, ties -> smaller index (matches jax.lax.top_k).
// All register indices compile-time (avoid scratch).
#define TOPK_TRY(key_, j_)                                                      \
  do {                                                                          \
    if ((key_) > tv[0] || ((key_) == tv[0] && (j_) < ti[0])) {                  \
      tv[0] = (key_); ti[0] = (j_);                                             \
      _Pragma("unroll")                                                         \
      for (int p_ = 0; p_ < K_ - 1; ++p_) {                                     \
        bool sw_ = (tv[p_] > tv[p_+1]) ||                                       \
                   (tv[p_] == tv[p_+1] && ti[p_] < ti[p_+1]);                   \
        float ta_ = sw_ ? tv[p_+1] : tv[p_];                                    \
        float tb_ = sw_ ? tv[p_]   : tv[p_+1];                                  \
        int   ia_ = sw_ ? ti[p_+1] : ti[p_];                                    \
        int   ib_ = sw_ ? ti[p_]   : ti[p_+1];                                  \
        tv[p_] = ta_; tv[p_+1] = tb_; ti[p_] = ia_; ti[p_+1] = ib_;             \
      }                                                                         \
    }                                                                           \
  } while (0)

// ---------------- Kernel 1: kNN on 3-D positions -> idx1 ----------------
// grid (P/256, B), block 256. Whole batch's points staged in LDS.
__global__ __launch_bounds__(256) void knn3_kernel(
    const float* __restrict__ pos, int* __restrict__ idx) {
  __shared__ float4 pts[P_];  // x,y,z,d2
  int b = blockIdx.y;
  const float* bp = pos + (size_t)b * P_ * 3;
  for (int j = threadIdx.x; j < P_; j += 256) {
    float x = bp[j * 3 + 0], y = bp[j * 3 + 1], z = bp[j * 3 + 2];
    pts[j] = make_float4(x, y, z, x * x + y * y + z * z);
  }
  __syncthreads();
  int i = blockIdx.x * 256 + threadIdx.x;
  float4 pi = pts[i];
  float tv[K_]; int ti[K_];
#pragma unroll
  for (int k = 0; k < K_; ++k) { tv[k] = -INFINITY; ti[k] = P_; }
  for (int j = 0; j < P_; ++j) {
    float4 pj = pts[j];  // LDS broadcast (uniform j)
    float neg = 2.f * (pi.x * pj.x + pi.y * pj.y + pi.z * pj.z) - pi.w - pj.w;
    TOPK_TRY(neg, j);
  }
  int* op = idx + ((size_t)b * P_ + i) * K_;
#pragma unroll
  for (int k = 0; k < K_; ++k) op[k] = ti[k];
}

// ---------------- Kernel 2: bv1[i][c] = pos_i @ W1[3:6] ----------------
__global__ __launch_bounds__(256) void bv1_kernel(
    const float* __restrict__ pos, const float* __restrict__ W1,
    float* __restrict__ bv) {
  int t = blockIdx.x * 256 + threadIdx.x;  // over B*P*64
  int c = t & 63, i = t >> 6;
  const float* p = pos + (size_t)i * 3;
  bv[t] = p[0] * W1[3 * 64 + c] + p[1] * W1[4 * 64 + c] + p[2] * W1[5 * 64 + c];
}

// ---------------- Kernel 3: layer-1 edge MLP + max over K -> x1, d2 -----
// grid (P/4, B), block 256 = 4 waves, one point per wave.
// pre-act(edge i,j)[c] = cv_i[c] + bv_j[c];   cv = pos@(W1a-W1b) + b1
// t = relu(pre*g1+bt1);  x1_i[n] = max_k (t_k @ W2)[n] + b2[n]
__global__ __launch_bounds__(256) void layer1_kernel(
    const float* __restrict__ pos, const float* __restrict__ W1,
    const float* __restrict__ b1, const float* __restrict__ g1,
    const float* __restrict__ bt1, const float* __restrict__ W2,
    const float* __restrict__ b2, const int* __restrict__ idx,
    const float* __restrict__ bv, float* __restrict__ x1,
    float* __restrict__ d2out) {
  __shared__ __align__(16) float W2t[64 * 68];  // W2t[n][c] = W2[c][n], stride 68
  __shared__ __align__(16) float T[4][K_ * 64];
  int b = blockIdx.y;
  int lane = threadIdx.x & 63;
  int w = threadIdx.x >> 6;
  for (int t = threadIdx.x; t < 64 * 64; t += 256) {
    int c = t >> 6, n = t & 63;
    W2t[n * 68 + c] = W2[c * 64 + n];
  }
  int i = blockIdx.x * 4 + w;
  size_t ip = (size_t)b * P_ + i;
  const float* posi = pos + ip * 3;
  float px = posi[0], py = posi[1], pz = posi[2];
  int c = lane;
  float cv = px * (W1[0 * 64 + c] - W1[3 * 64 + c]) +
             py * (W1[1 * 64 + c] - W1[4 * 64 + c]) +
             pz * (W1[2 * 64 + c] - W1[5 * 64 + c]) + b1[c];
  float g = g1[c], bt = bt1[c];
  const int* ji = idx + ip * K_;
  const float* bvb = bv + (size_t)b * P_ * 64;
  for (int k = 0; k < K_; ++k) {
    int j = ji[k];
    float t = cv + bvb[(size_t)j * 64 + c];
    t = fmaxf(t * g + bt, 0.f);
    T[w][k * 64 + c] = t;
  }
  __syncthreads();
  float acc[K_];
#pragma unroll
  for (int k = 0; k < K_; ++k) acc[k] = 0.f;
  const float4* Trow = (const float4*)&T[w][0];
#pragma unroll
  for (int c4 = 0; c4 < 16; ++c4) {
    float4 wv = *(const float4*)&W2t[lane * 68 + c4 * 4];
#pragma unroll
    for (int k = 0; k < K_; ++k) {
      float4 tvv = Trow[k * 16 + c4];  // broadcast
      acc[k] += tvv.x * wv.x + tvv.y * wv.y + tvv.z * wv.z + tvv.w * wv.w;
    }
  }
  float m = -INFINITY;
#pragma unroll
  for (int k = 0; k < K_; ++k) m = fmaxf(m, acc[k]);
  m += b2[lane];
  x1[ip * 64 + lane] = m;
  float s = m * m;
#pragma unroll
  for (int off = 32; off; off >>= 1) s += __shfl_xor(s, off, 64);
  if (lane == 0) d2out[ip] = s;
}

// ---------------- Kernel 4: kNN on 64-D x1 -> idx2 ----------------
// grid (P/256, B), block 256. One row per thread, j-tiles of 128 in LDS.
// key = 2*dot(x_i,x_j) - d2_j  (d2_i const per row; order preserved)
__global__ __launch_bounds__(256) void knn64_kernel(
    const float* __restrict__ x1, const float* __restrict__ d2g,
    int* __restrict__ idx) {
  __shared__ __align__(16) float tile[128 * 64];
  __shared__ float d2s[128];
  int b = blockIdx.y;
  const float* xb = x1 + (size_t)b * P_ * 64;
  int i = blockIdx.x * 256 + threadIdx.x;
  float4 xi[16];
  const float4* xrow = (const float4*)(xb + (size_t)i * 64);
#pragma unroll
  for (int q = 0; q < 16; ++q) xi[q] = xrow[q];
  float tv[K_]; int ti[K_];
#pragma unroll
  for (int k = 0; k < K_; ++k) { tv[k] = -INFINITY; ti[k] = P_; }
  for (int j0 = 0; j0 < P_; j0 += 128) {
    __syncthreads();
    const float4* src = (const float4*)(xb + (size_t)j0 * 64);
    float4* dst = (float4*)tile;
    for (int v = threadIdx.x; v < 128 * 16; v += 256) dst[v] = src[v];
    if (threadIdx.x < 128) d2s[threadIdx.x] = d2g[(size_t)b * P_ + j0 + threadIdx.x];
    __syncthreads();
    for (int jj = 0; jj < 128; ++jj) {
      const float4* xj = (const float4*)(tile + jj * 64);  // broadcast
      float a0 = 0.f, a1 = 0.f, a2 = 0.f, a3 = 0.f;
#pragma unroll
      for (int q = 0; q < 16; ++q) {
        float4 a = xi[q]; float4 bq = xj[q];
        a0 += a.x * bq.x; a1 += a.y * bq.y; a2 += a.z * bq.z; a3 += a.w * bq.w;
      }
      float key = 2.f * ((a0 + a1) + (a2 + a3)) - d2s[jj];
      int j = j0 + jj;
      TOPK_TRY(key, j);
    }
  }
  int* op = idx + ((size_t)b * P_ + i) * K_;
#pragma unroll
  for (int k = 0; k < K_; ++k) op[k] = ti[k];
}

// ---------------- Kernel 5: e2 = x1@(W3a-W3b)+b3, bb2 = x1@W3b ----------
// block 256, 16 points/block; thread = (n, which-half), 16 points each.
__global__ __launch_bounds__(256) void ebb_kernel(
    const float* __restrict__ x1, const float* __restrict__ W3,
    const float* __restrict__ b3, float* __restrict__ e2,
    float* __restrict__ bb2) {
  __shared__ float xs[16 * 64];
  size_t p0 = (size_t)blockIdx.x * 16;
  for (int v = threadIdx.x; v < 16 * 64; v += 256) xs[v] = x1[p0 * 64 + v];
  __syncthreads();
  int n = threadIdx.x & 127;
  int which = threadIdx.x >> 7;  // wave-uniform
  float acc[16];
#pragma unroll
  for (int p = 0; p < 16; ++p) acc[p] = 0.f;
  for (int c = 0; c < 64; ++c) {
    float wa = W3[c * 128 + n];
    float wb = W3[(64 + c) * 128 + n];
    float wv = which ? wb : (wa - wb);
#pragma unroll
    for (int p = 0; p < 16; ++p) acc[p] += xs[p * 64 + c] * wv;
  }
  float bias = which ? 0.f : b3[n];
  float* dst = which ? bb2 : e2;
#pragma unroll
  for (int p = 0; p < 16; ++p) dst[(p0 + p) * 128 + n] = acc[p] + bias;
}

// ---------------- Kernel 6: x2 gather-max + hp@Wl + per-tile max --------
// grid (P/32, B), block 256. hp = [x1 | e2 + max_k bb2[j_k]] (192).
__global__ __launch_bounds__(256) void final_kernel(
    const float* __restrict__ x1, const float* __restrict__ e2,
    const float* __restrict__ bb2, const int* __restrict__ idx,
    const float* __restrict__ Wl, const float* __restrict__ bl,
    float* __restrict__ partial) {
  __shared__ float hp[32][192];
  __shared__ float smax[2][128];
  int b = blockIdx.y;
  int i0 = blockIdx.x * 32;
  size_t gp0 = (size_t)b * P_ + i0;
  for (int v = threadIdx.x; v < 32 * 64; v += 256) {
    int p = v >> 6, c = v & 63;
    hp[p][c] = x1[(gp0 + p) * 64 + c];
  }
  for (int v = threadIdx.x; v < 32 * 128; v += 256) {
    int p = v >> 7, n = v & 127;
    size_t gp = gp0 + p;
    const int* ji = idx + gp * K_;
    float m = -INFINITY;
    for (int k = 0; k < K_; ++k) {
      int j = ji[k];
      m = fmaxf(m, bb2[((size_t)b * P_ + j) * 128 + n]);
    }
    hp[p][64 + n] = e2[gp * 128 + n] + m;
  }
  __syncthreads();
  int n = threadIdx.x & 127;
  int pg = threadIdx.x >> 7;
  float acc[16];
#pragma unroll
  for (int p = 0; p < 16; ++p) acc[p] = 0.f;
  for (int c = 0; c < 192; ++c) {
    float wv = Wl[c * 128 + n];
#pragma unroll
    for (int p = 0; p < 16; ++p) acc[p] += hp[pg * 16 + p][c] * wv;
  }
  float m = -INFINITY;
#pragma unroll
  for (int p = 0; p < 16; ++p) m = fmaxf(m, acc[p]);
  smax[pg][n] = m;
  __syncthreads();
  if (threadIdx.x < 128) {
    float v = fmaxf(smax[0][n], smax[1][n]) + bl[n];
    partial[((size_t)b * 64 + blockIdx.x) * 128 + n] = v;
  }
}

// ---------------- Kernel 7: reduce partial maxes -> out (B,128) ---------
__global__ __launch_bounds__(256) void reduce_kernel(
    const float* __restrict__ partial, float* __restrict__ out) {
  int t = blockIdx.x * 256 + threadIdx.x;  // 4096
  int b = t >> 7, n = t & 127;
  float m = -INFINITY;
  for (int tb = 0; tb < 64; ++tb)
    m = fmaxf(m, partial[((size_t)b * 64 + tb) * 128 + n]);
  out[t] = m;
}

extern "C" void kernel_launch(void* const* d_in, const int* in_sizes, int n_in,
                              void* d_out, int out_size, void* d_ws,
                              size_t ws_size, hipStream_t stream) {
  (void)in_sizes; (void)n_in; (void)out_size; (void)ws_size;
  const float* pos = (const float*)d_in[0];
  const float* W1  = (const float*)d_in[1];
  const float* b1  = (const float*)d_in[2];
  const float* g1  = (const float*)d_in[3];
  const float* bt1 = (const float*)d_in[4];
  const float* W2  = (const float*)d_in[5];
  const float* b2  = (const float*)d_in[6];
  const float* W3  = (const float*)d_in[7];
  const float* b3  = (const float*)d_in[8];
  const float* Wl  = (const float*)d_in[9];
  const float* bl  = (const float*)d_in[10];
  float* out = (float*)d_out;

  // Workspace layout (bytes). Peak 90,439,680 B (~86.3 MB).
  char* w = (char*)d_ws;
  int*   idxp  = (int*)(w + 0);             //  5,242,880  idx1 then idx2
  float* x1p   = (float*)(w + 5242880);     // 16,777,216
  float* bv1p  = (float*)(w + 22020096);    // 33,554,432 region: bv1 then bb2
  float* bb2p  = bv1p;
  float* d2p   = (float*)(w + 55574528);    //    262,144
  float* e2p   = (float*)(w + 55836672);    // 33,554,432
  float* partp = (float*)(w + 89391104);    //  1,048,576

  knn3_kernel<<<dim3(P_ / 256, B_), 256, 0, stream>>>(pos, idxp);
  bv1_kernel<<<dim3(B_ * P_ * 64 / 256), 256, 0, stream>>>(pos, W1, bv1p);
  layer1_kernel<<<dim3(P_ / 4, B_), 256, 0, stream>>>(
      pos, W1, b1, g1, bt1, W2, b2, idxp, bv1p, x1p, d2p);
  knn64_kernel<<<dim3(P_ / 256, B_), 256, 0, stream>>>(x1p, d2p, idxp);
  ebb_kernel<<<dim3(B_ * P_ / 16), 256, 0, stream>>>(x1p, W3, b3, e2p, bb2p);
  final_kernel<<<dim3(P_ / 32, B_), 256, 0, stream>>>(
      x1p, e2p, bb2p, idxp, Wl, bl, partp);
  reduce_kernel<<<dim3(16), 256, 0, stream>>>(partp, out);
}

// Round 2
// 2105.458 us; speedup vs baseline: 15.5053x; 15.5053x over previous
//
#include <hip/hip_runtime.h>

#define B_ 32
#define P_ 2048
#define K_ 20

// ---- order-preserving (key, idx) packing -------------------------------
// larger key wins; ties -> smaller idx wins (matches jax.lax.top_k).
__device__ inline unsigned long long pack_key(float key, int j) {
  unsigned u = __float_as_uint(key);
  unsigned m = ((unsigned)((int)u >> 31)) | 0x80000000u;
  u ^= m;  // monotone float->uint
  return ((unsigned long long)u << 32) | (unsigned)(~j);
}

// Sorted-ascending top-K list (t[0]=worst, t[K-1]=best), in registers.
// Shift-insert with independent per-stage selects (ILP-friendly).
__device__ inline void topk_insert(unsigned long long (&t)[K_],
                                   unsigned long long x) {
  if (x > t[0]) {
#pragma unroll
    for (int p = 0; p < K_ - 1; ++p) {
      bool c = x > t[p + 1];                       // x belongs above slot p
      unsigned long long mx = t[p] > x ? t[p] : x; // max(old[p], x)
      t[p] = c ? t[p + 1] : mx;
    }
    t[K_ - 1] = t[K_ - 1] > x ? t[K_ - 1] : x;
  }
}

// ---------------- Kernel 1: kNN on 3-D positions -> idx1 ----------------
// grid (P/128, B), block 256: 128 rows x 2 j-halves. Bitonic merge via LDS.
__global__ __launch_bounds__(256) void knn3_kernel(
    const float* __restrict__ pos, int* __restrict__ idx) {
  __shared__ float4 pts[P_];                         // 32 KB: x,y,z,d2
  __shared__ unsigned long long lists[128][K_];      // 20 KB: half-1 lists
  int b = blockIdx.y;
  const float* bp = pos + (size_t)b * P_ * 3;
  for (int j = threadIdx.x; j < P_; j += 256) {
    float x = bp[j * 3 + 0], y = bp[j * 3 + 1], z = bp[j * 3 + 2];
    pts[j] = make_float4(x, y, z, x * x + y * y + z * z);
  }
  __syncthreads();
  int q = threadIdx.x & 127;           // row within block
  int h = threadIdx.x >> 7;            // j-half
  int r = blockIdx.x * 128 + q;        // global row
  float4 pi = pts[r];
  unsigned long long t[K_];
#pragma unroll
  for (int k = 0; k < K_; ++k) t[k] = 0ULL;
  int j0 = h * (P_ / 2);
  for (int j = j0; j < j0 + P_ / 2; ++j) {
    float4 pj = pts[j];  // LDS broadcast (uniform j within half-wave group)
    float key = 2.f * (pi.x * pj.x + pi.y * pj.y + pi.z * pj.z) - pj.w;
    topk_insert(t, pack_key(key, j));
  }
  if (h == 1) {
#pragma unroll
    for (int k = 0; k < K_; ++k) lists[q][k] = t[k];
  }
  __syncthreads();
  if (h == 0) {
    int* op = idx + ((size_t)b * P_ + r) * K_;
#pragma unroll
    for (int k = 0; k < K_; ++k) {
      unsigned long long o = lists[q][K_ - 1 - k];
      unsigned long long m = t[k] > o ? t[k] : o;   // bitonic top-K merge
      op[k] = (int)(~(unsigned)m);
    }
  }
}

// ---------------- Kernel 2: bv1[i][c] = pos_i @ W1[3:6] ----------------
__global__ __launch_bounds__(256) void bv1_kernel(
    const float* __restrict__ pos, const float* __restrict__ W1,
    float* __restrict__ bv) {
  int t = blockIdx.x * 256 + threadIdx.x;  // over B*P*64
  int c = t & 63, i = t >> 6;
  const float* p = pos + (size_t)i * 3;
  bv[t] = p[0] * W1[3 * 64 + c] + p[1] * W1[4 * 64 + c] + p[2] * W1[5 * 64 + c];
}

// ---------------- Kernel 3: layer-1 edge MLP + max over K -> x1, d2 -----
// grid (P/4, B), block 256 = 4 waves, one point per wave.
// pre-act(edge i,j)[c] = cv_i[c] + bv_j[c];   cv = pos@(W1a-W1b) + b1
// t = relu(pre*g1+bt1);  x1_i[n] = max_k (t_k @ W2)[n] + b2[n]
__global__ __launch_bounds__(256) void layer1_kernel(
    const float* __restrict__ pos, const float* __restrict__ W1,
    const float* __restrict__ b1, const float* __restrict__ g1,
    const float* __restrict__ bt1, const float* __restrict__ W2,
    const float* __restrict__ b2, const int* __restrict__ idx,
    const float* __restrict__ bv, float* __restrict__ x1,
    float* __restrict__ d2out) {
  __shared__ __align__(16) float W2t[64 * 68];  // W2t[n][c] = W2[c][n], stride 68
  __shared__ __align__(16) float T[4][K_ * 64];
  int b = blockIdx.y;
  int lane = threadIdx.x & 63;
  int w = threadIdx.x >> 6;
  for (int t = threadIdx.x; t < 64 * 64; t += 256) {
    int c = t >> 6, n = t & 63;
    W2t[n * 68 + c] = W2[c * 64 + n];
  }
  int i = blockIdx.x * 4 + w;
  size_t ip = (size_t)b * P_ + i;
  const float* posi = pos + ip * 3;
  float px = posi[0], py = posi[1], pz = posi[2];
  int c = lane;
  float cv = px * (W1[0 * 64 + c] - W1[3 * 64 + c]) +
             py * (W1[1 * 64 + c] - W1[4 * 64 + c]) +
             pz * (W1[2 * 64 + c] - W1[5 * 64 + c]) + b1[c];
  float g = g1[c], bt = bt1[c];
  const int* ji = idx + ip * K_;
  const float* bvb = bv + (size_t)b * P_ * 64;
  for (int k = 0; k < K_; ++k) {
    int j = ji[k];
    float t = cv + bvb[(size_t)j * 64 + c];
    t = fmaxf(t * g + bt, 0.f);
    T[w][k * 64 + c] = t;
  }
  __syncthreads();
  float acc[K_];
#pragma unroll
  for (int k = 0; k < K_; ++k) acc[k] = 0.f;
  const float4* Trow = (const float4*)&T[w][0];
#pragma unroll
  for (int c4 = 0; c4 < 16; ++c4) {
    float4 wv = *(const float4*)&W2t[lane * 68 + c4 * 4];
#pragma unroll
    for (int k = 0; k < K_; ++k) {
      float4 tvv = Trow[k * 16 + c4];  // broadcast
      acc[k] += tvv.x * wv.x + tvv.y * wv.y + tvv.z * wv.z + tvv.w * wv.w;
    }
  }
  float m = -INFINITY;
#pragma unroll
  for (int k = 0; k < K_; ++k) m = fmaxf(m, acc[k]);
  m += b2[lane];
  x1[ip * 64 + lane] = m;
  float s = m * m;
#pragma unroll
  for (int off = 32; off; off >>= 1) s += __shfl_xor(s, off, 64);
  if (lane == 0) d2out[ip] = s;
}

// ---------------- Kernel 4: kNN on 64-D x1 -> idx2 ----------------
// grid (P/128, B), block 256: 128 rows x 2 j-halves, 64-wide j-tiles in LDS.
// key = 2*dot(x_i,x_j) - d2_j  (d2_i const per row; order preserved)
__global__ __launch_bounds__(256) void knn64_kernel(
    const float* __restrict__ x1, const float* __restrict__ d2g,
    int* __restrict__ idx) {
  __shared__ __align__(16) float tile[2][64 * 64];   // 32 KB
  __shared__ float d2s[2][64];
  __shared__ unsigned long long lists[128][K_];      // 20 KB
  int b = blockIdx.y;
  const float* xb = x1 + (size_t)b * P_ * 64;
  int q = threadIdx.x & 127;
  int h = threadIdx.x >> 7;
  int r = blockIdx.x * 128 + q;
  float4 xi[16];
  const float4* xrow = (const float4*)(xb + (size_t)r * 64);
#pragma unroll
  for (int v = 0; v < 16; ++v) xi[v] = xrow[v];
  unsigned long long t[K_];
#pragma unroll
  for (int k = 0; k < K_; ++k) t[k] = 0ULL;
  int base = h * (P_ / 2);
  for (int t0 = 0; t0 < P_ / 2; t0 += 64) {
    __syncthreads();
    const float4* src = (const float4*)(xb + (size_t)(base + t0) * 64);
    float4* dst = (float4*)tile[h];
    for (int v = q; v < 64 * 16; v += 128) dst[v] = src[v];
    if (q < 64) d2s[h][q] = d2g[(size_t)b * P_ + base + t0 + q];
    __syncthreads();
    for (int jj = 0; jj < 64; ++jj) {
      const float4* xj = (const float4*)(&tile[h][jj * 64]);  // broadcast
      float a0 = 0.f, a1 = 0.f, a2 = 0.f, a3 = 0.f;
#pragma unroll
      for (int v = 0; v < 16; ++v) {
        float4 a = xi[v]; float4 bq = xj[v];
        a0 += a.x * bq.x; a1 += a.y * bq.y; a2 += a.z * bq.z; a3 += a.w * bq.w;
      }
      float key = 2.f * ((a0 + a1) + (a2 + a3)) - d2s[h][jj];
      topk_insert(t, pack_key(key, base + t0 + jj));
    }
  }
  if (h == 1) {
#pragma unroll
    for (int k = 0; k < K_; ++k) lists[q][k] = t[k];
  }
  __syncthreads();
  if (h == 0) {
    int* op = idx + ((size_t)b * P_ + r) * K_;
#pragma unroll
    for (int k = 0; k < K_; ++k) {
      unsigned long long o = lists[q][K_ - 1 - k];
      unsigned long long m = t[k] > o ? t[k] : o;
      op[k] = (int)(~(unsigned)m);
    }
  }
}

// ---------------- Kernel 5: e2 = x1@(W3a-W3b)+b3, bb2 = x1@W3b ----------
// block 256, 16 points/block; thread = (n, which-half), 16 points each.
__global__ __launch_bounds__(256) void ebb_kernel(
    const float* __restrict__ x1, const float* __restrict__ W3,
    const float* __restrict__ b3, float* __restrict__ e2,
    float* __restrict__ bb2) {
  __shared__ float xs[16 * 64];
  size_t p0 = (size_t)blockIdx.x * 16;
  for (int v = threadIdx.x; v < 16 * 64; v += 256) xs[v] = x1[p0 * 64 + v];
  __syncthreads();
  int n = threadIdx.x & 127;
  int which = threadIdx.x >> 7;  // wave-uniform
  float acc[16];
#pragma unroll
  for (int p = 0; p < 16; ++p) acc[p] = 0.f;
  for (int c = 0; c < 64; ++c) {
    float wa = W3[c * 128 + n];
    float wb = W3[(64 + c) * 128 + n];
    float wv = which ? wb : (wa - wb);
#pragma unroll
    for (int p = 0; p < 16; ++p) acc[p] += xs[p * 64 + c] * wv;
  }
  float bias = which ? 0.f : b3[n];
  float* dst = which ? bb2 : e2;
#pragma unroll
  for (int p = 0; p < 16; ++p) dst[(p0 + p) * 128 + n] = acc[p] + bias;
}

// ---------------- Kernel 6: x2 gather-max + hp@Wl + per-tile max --------
// grid (P/32, B), block 256. hp = [x1 | e2 + max_k bb2[j_k]] (192).
__global__ __launch_bounds__(256) void final_kernel(
    const float* __restrict__ x1, const float* __restrict__ e2,
    const float* __restrict__ bb2, const int* __restrict__ idx,
    const float* __restrict__ Wl, const float* __restrict__ bl,
    float* __restrict__ partial) {
  __shared__ float hp[32][192];
  __shared__ float smax[2][128];
  int b = blockIdx.y;
  int i0 = blockIdx.x * 32;
  size_t gp0 = (size_t)b * P_ + i0;
  for (int v = threadIdx.x; v < 32 * 64; v += 256) {
    int p = v >> 6, c = v & 63;
    hp[p][c] = x1[(gp0 + p) * 64 + c];
  }
  for (int v = threadIdx.x; v < 32 * 128; v += 256) {
    int p = v >> 7, n = v & 127;
    size_t gp = gp0 + p;
    const int* ji = idx + gp * K_;
    float m = -INFINITY;
    for (int k = 0; k < K_; ++k) {
      int j = ji[k];
      m = fmaxf(m, bb2[((size_t)b * P_ + j) * 128 + n]);
    }
    hp[p][64 + n] = e2[gp * 128 + n] + m;
  }
  __syncthreads();
  int n = threadIdx.x & 127;
  int pg = threadIdx.x >> 7;
  float acc[16];
#pragma unroll
  for (int p = 0; p < 16; ++p) acc[p] = 0.f;
  for (int c = 0; c < 192; ++c) {
    float wv = Wl[c * 128 + n];
#pragma unroll
    for (int p = 0; p < 16; ++p) acc[p] += hp[pg * 16 + p][c] * wv;
  }
  float m = -INFINITY;
#pragma unroll
  for (int p = 0; p < 16; ++p) m = fmaxf(m, acc[p]);
  smax[pg][n] = m;
  __syncthreads();
  if (threadIdx.x < 128) {
    float v = fmaxf(smax[0][n], smax[1][n]) + bl[n];
    partial[((size_t)b * 64 + blockIdx.x) * 128 + n] = v;
  }
}

// ---------------- Kernel 7: reduce partial maxes -> out (B,128) ---------
__global__ __launch_bounds__(256) void reduce_kernel(
    const float* __restrict__ partial, float* __restrict__ out) {
  int t = blockIdx.x * 256 + threadIdx.x;  // 4096
  int b = t >> 7, n = t & 127;
  float m = -INFINITY;
  for (int tb = 0; tb < 64; ++tb)
    m = fmaxf(m, partial[((size_t)b * 64 + tb) * 128 + n]);
  out[t] = m;
}

extern "C" void kernel_launch(void* const* d_in, const int* in_sizes, int n_in,
                              void* d_out, int out_size, void* d_ws,
                              size_t ws_size, hipStream_t stream) {
  (void)in_sizes; (void)n_in; (void)out_size; (void)ws_size;
  const float* pos = (const float*)d_in[0];
  const float* W1  = (const float*)d_in[1];
  const float* b1  = (const float*)d_in[2];
  const float* g1  = (const float*)d_in[3];
  const float* bt1 = (const float*)d_in[4];
  const float* W2  = (const float*)d_in[5];
  const float* b2  = (const float*)d_in[6];
  const float* W3  = (const float*)d_in[7];
  const float* b3  = (const float*)d_in[8];
  const float* Wl  = (const float*)d_in[9];
  const float* bl  = (const float*)d_in[10];
  float* out = (float*)d_out;

  // Workspace layout (bytes). Peak ~86.3 MB.
  char* w = (char*)d_ws;
  int*   idxp  = (int*)(w + 0);             //  5,242,880  idx1 then idx2
  float* x1p   = (float*)(w + 5242880);     // 16,777,216
  float* bv1p  = (float*)(w + 22020096);    // 33,554,432 region: bv1 then bb2
  float* bb2p  = bv1p;
  float* d2p   = (float*)(w + 55574528);    //    262,144
  float* e2p   = (float*)(w + 55836672);    // 33,554,432
  float* partp = (float*)(w + 89391104);    //  1,048,576

  knn3_kernel<<<dim3(P_ / 128, B_), 256, 0, stream>>>(pos, idxp);
  bv1_kernel<<<dim3(B_ * P_ * 64 / 256), 256, 0, stream>>>(pos, W1, bv1p);
  layer1_kernel<<<dim3(P_ / 4, B_), 256, 0, stream>>>(
      pos, W1, b1, g1, bt1, W2, b2, idxp, bv1p, x1p, d2p);
  knn64_kernel<<<dim3(P_ / 128, B_), 256, 0, stream>>>(x1p, d2p, idxp);
  ebb_kernel<<<dim3(B_ * P_ / 16), 256, 0, stream>>>(x1p, W3, b3, e2p, bb2p);
  final_kernel<<<dim3(P_ / 32, B_), 256, 0, stream>>>(
      x1p, e2p, bb2p, idxp, Wl, bl, partp);
  reduce_kernel<<<dim3(16), 256, 0, stream>>>(partp, out);
}